// Round 1
// baseline (296.270 us; speedup 1.0000x reference)
//
#include <hip/hip_runtime.h>

typedef unsigned int u32;
typedef unsigned long long u64;
typedef unsigned char u8;

#define NB 8
#define NA 110000
#define NC 80
#define PRE 1000
#define TOPK 200
#define CAND_MAX 2048

static_assert(sizeof(float) == 4, "");

// ---- workspace layout (bytes) ----
#define OFF_HIST1   0u          // 8*2048*4 = 65536
#define OFF_HIST2   65536u      // 8*2048*4 = 65536
#define OFF_HIST3   131072u     // 8*1024*4 = 32768
#define OFF_CANDCNT 163840u     // 8*4
#define OFF_STATE   163872u     // 8*4*4 = 128  (prefix, cnt_gt, unused, takeall)
#define ZERO_BYTES  164000u
#define OFF_CAND    164096u     // 8*2048*8 = 131072
#define OFF_BOXES   295168u     // 8*1024*4*4 = 131072
#define OFF_SCORE   426240u     // 8*1024*4 = 32768
#define OFF_CLSSEL  459008u     // 8*1024*4 = 32768
#define OFF_VBITS   491776u     // 8*110000*4 = 3520000
#define OFF_CLS     4011776u    // 8*110000*1 = 880000  -> total 4891776

// ============ K1: per-anchor max/argmax over 80 classes + pass-1 histogram ============
__global__ __launch_bounds__(256) void k_reduce(const float* __restrict__ conf,
                                                u32* __restrict__ vbits,
                                                u8* __restrict__ cls,
                                                u32* __restrict__ ghist) {
    const int BPI = (NA + 1023) / 1024;   // 108
    int b = blockIdx.x / BPI;
    int ch = blockIdx.x % BPI;
    __shared__ u32 h[2048];
    for (int i = threadIdx.x; i < 2048; i += 256) h[i] = 0u;
    __syncthreads();
    int base = ch * 1024;
    for (int k = 0; k < 4; ++k) {
        int a = base + k * 256 + threadIdx.x;
        if (a < NA) {
            const float4* p = reinterpret_cast<const float4*>(conf + ((size_t)b * NA + a) * NC);
            float m = -1.0f; int mi = 0;
            #pragma unroll
            for (int i = 0; i < 20; ++i) {
                float4 v = p[i];
                if (v.x > m) { m = v.x; mi = 4 * i + 0; }
                if (v.y > m) { m = v.y; mi = 4 * i + 1; }
                if (v.z > m) { m = v.z; mi = 4 * i + 2; }
                if (v.w > m) { m = v.w; mi = 4 * i + 3; }
            }
            cls[(size_t)b * NA + a] = (u8)mi;
            u32 vb = (m > 0.05f) ? __float_as_uint(m) : 0u;
            vbits[(size_t)b * NA + a] = vb;
            if (vb) atomicAdd(&h[vb >> 21], 1u);
        }
    }
    __syncthreads();
    for (int i = threadIdx.x; i < 2048; i += 256)
        if (h[i]) atomicAdd(&ghist[b * 2048 + i], h[i]);
}

// ============ histogram passes 2/3 over stored vbits ============
__global__ __launch_bounds__(256) void k_hist(const u32* __restrict__ vbits,
                                              const u32* __restrict__ state,
                                              u32* __restrict__ ghist,
                                              int nb, int matchShift, int bucketShift) {
    const int BPI = (NA + 2047) / 2048;   // 54
    int b = blockIdx.x / BPI;
    int ch = blockIdx.x % BPI;
    if (state[b * 4 + 3]) return;               // take-all: nothing to refine (uniform)
    u32 prefix = state[b * 4 + 0];
    __shared__ u32 h[2048];
    for (int i = threadIdx.x; i < nb; i += 256) h[i] = 0u;
    __syncthreads();
    int base = ch * 2048;
    for (int k = 0; k < 8; ++k) {
        int a = base + k * 256 + threadIdx.x;
        if (a < NA) {
            u32 vb = vbits[(size_t)b * NA + a];
            if (vb && ((vb >> matchShift) == (prefix >> matchShift)))
                atomicAdd(&h[(vb >> bucketShift) & (u32)(nb - 1)], 1u);
        }
    }
    __syncthreads();
    for (int i = threadIdx.x; i < nb; i += 256)
        if (h[i]) atomicAdd(&ghist[b * nb + i], h[i]);
}

// ============ select the bucket containing the PRE-th largest ============
__global__ __launch_bounds__(256) void k_select(u32* __restrict__ state,
                                                const u32* __restrict__ ghist,
                                                int nb, int mergeShift) {
    int b = blockIdx.x;
    u32* st = state + b * 4;
    if (st[3]) return;                           // uniform
    __shared__ u32 h[2048];
    __shared__ u32 part[256];
    int P = nb / 256;
    for (int i = threadIdx.x; i < nb; i += 256) h[i] = ghist[b * nb + i];
    __syncthreads();
    u32 s = 0;
    for (int j = 0; j < P; ++j) s += h[nb - 1 - (threadIdx.x * P + j)];
    part[threadIdx.x] = s;
    __syncthreads();
    if (threadIdx.x == 0) {
        u32 target = (u32)PRE - st[1];           // >=1 by construction
        u32 cum = 0; int tstar = -1;
        for (int t = 0; t < 256; ++t) {
            if (cum + part[t] >= target) { tstar = t; break; }
            cum += part[t];
        }
        if (tstar < 0) {
            st[3] = 1u;                          // fewer than PRE valid in total
        } else {
            for (int j = 0; j < P; ++j) {
                int bk = nb - 1 - (tstar * P + j);
                u32 c = h[bk];
                if (cum + c >= target) {
                    st[0] |= ((u32)bk) << mergeShift;
                    st[1] += cum;                // count strictly greater so far
                    break;
                }
                cum += c;
            }
        }
    }
}

// ============ compact candidates with vbits >= T into 64-bit keys ============
__global__ __launch_bounds__(256) void k_compact(const u32* __restrict__ vbits,
                                                 const u32* __restrict__ state,
                                                 u64* __restrict__ cand,
                                                 u32* __restrict__ candCnt) {
    const int BPI = (NA + 2047) / 2048;   // 54
    int b = blockIdx.x / BPI;
    int ch = blockIdx.x % BPI;
    u32 T = state[b * 4 + 3] ? 1u : state[b * 4 + 0];
    int base = ch * 2048;
    for (int k = 0; k < 8; ++k) {
        int a = base + k * 256 + threadIdx.x;
        if (a < NA) {
            u32 vb = vbits[(size_t)b * NA + a];
            if (vb >= T) {
                u32 slot = atomicAdd(&candCnt[b], 1u);
                if (slot < CAND_MAX)
                    cand[(size_t)b * CAND_MAX + slot] =
                        ((u64)vb << 32) | (u64)(0xFFFFFFFFu - (u32)a);
            }
        }
    }
}

// ============ in-LDS bitonic sort (descending) of up to 2048 keys ============
__global__ __launch_bounds__(256) void k_sort(u64* __restrict__ cand,
                                              const u32* __restrict__ candCnt) {
    int b = blockIdx.x;
    __shared__ u64 key[CAND_MAX];
    int n = (int)candCnt[b]; if (n > CAND_MAX) n = CAND_MAX;
    for (int i = threadIdx.x; i < CAND_MAX; i += 256)
        key[i] = (i < n) ? cand[(size_t)b * CAND_MAX + i] : 0ull;
    __syncthreads();
    for (int k = 2; k <= CAND_MAX; k <<= 1) {
        for (int j = k >> 1; j > 0; j >>= 1) {
            for (int i = threadIdx.x; i < CAND_MAX; i += 256) {
                int l = i ^ j;
                if (l > i) {
                    u64 a = key[i], c = key[l];
                    bool desc = ((i & k) == 0);
                    if (desc ? (a < c) : (a > c)) { key[i] = c; key[l] = a; }
                }
            }
            __syncthreads();
        }
    }
    for (int i = threadIdx.x; i < CAND_MAX; i += 256)
        cand[(size_t)b * CAND_MAX + i] = key[i];
}

// ============ decode boxes for the sorted top-1000 ============
__global__ __launch_bounds__(256) void k_finalize(const u64* __restrict__ cand,
                                                  const u32* __restrict__ candCnt,
                                                  const u8* __restrict__ cls,
                                                  const float* __restrict__ anchors,
                                                  const float* __restrict__ regs,
                                                  float* __restrict__ boxes,
                                                  float* __restrict__ score,
                                                  int* __restrict__ clsSel) {
    int b = blockIdx.x;
    int n = (int)candCnt[b]; if (n > CAND_MAX) n = CAND_MAX;
    int nsel = n < PRE ? n : PRE;
    for (int r = threadIdx.x; r < PRE; r += 256) {
        if (r < nsel) {
            u64 key = cand[(size_t)b * CAND_MAX + r];
            u32 vb = (u32)(key >> 32);
            u32 idx = 0xFFFFFFFFu - (u32)(key & 0xFFFFFFFFull);
            float4 an = reinterpret_cast<const float4*>(anchors)[idx];
            float4 rg = reinterpret_cast<const float4*>(regs)[(size_t)b * NA + idx];
            float ya = (an.x + an.z) * 0.5f;
            float xa = (an.y + an.w) * 0.5f;
            float ha = an.z - an.x;
            float wa = an.w - an.y;
            float w  = expf(rg.w) * wa;
            float h  = expf(rg.z) * ha;
            float yc = rg.x * ha + ya;
            float xc = rg.y * wa + xa;
            float x1 = xc - w * 0.5f, y1 = yc - h * 0.5f;
            float x2 = xc + w * 0.5f, y2 = yc + h * 0.5f;
            const float inv = 1.0f / 512.0f;
            float4 bx;
            bx.x = fminf(fmaxf(x1, 0.0f), 512.0f) * inv;
            bx.y = fminf(fmaxf(y1, 0.0f), 512.0f) * inv;
            bx.z = fminf(fmaxf(x2, 0.0f), 512.0f) * inv;
            bx.w = fminf(fmaxf(y2, 0.0f), 512.0f) * inv;
            reinterpret_cast<float4*>(boxes)[(size_t)b * 1024 + r] = bx;
            score[(size_t)b * 1024 + r] = __uint_as_float(vb);
            clsSel[(size_t)b * 1024 + r] = (int)cls[(size_t)b * NA + idx];
        } else {
            clsSel[(size_t)b * 1024 + r] = -1;
            score[(size_t)b * 1024 + r] = 0.0f;
        }
    }
}

// ============ per-(image,class) greedy NMS + top-200 emission ============
// One wave per class; cross-class IoU is exactly 0 in the reference (class
// offset >= 2 with boxes in [0,1]), so suppression is block-diagonal per class.
// IoU computed on OFFSET coords (b + ci*2) to bit-match reference arithmetic.
__global__ __launch_bounds__(256) void k_nms(const float* __restrict__ boxes,
                                             const float* __restrict__ score,
                                             const int* __restrict__ clsSel,
                                             float* __restrict__ out) {
    int b = blockIdx.x / (NC / 4);
    int wave = threadIdx.x >> 6;
    int lane = threadIdx.x & 63;
    int ci = (blockIdx.x % (NC / 4)) * 4 + wave;
    __shared__ float mem[4][256][5];

    // gather members of class ci in sorted-rank order
    int m = 0;
    for (int ch = 0; ch < 16; ++ch) {
        int r = ch * 64 + lane;
        bool match = (r < PRE) && (clsSel[(size_t)b * 1024 + r] == ci);
        u64 bal = __ballot(match);
        int pos = m + (int)__popcll(bal & (((u64)1 << lane) - 1ull));
        if (match && pos < 256) {
            float4 bx = reinterpret_cast<const float4*>(boxes)[(size_t)b * 1024 + r];
            mem[wave][pos][0] = bx.x; mem[wave][pos][1] = bx.y;
            mem[wave][pos][2] = bx.z; mem[wave][pos][3] = bx.w;
            mem[wave][pos][4] = score[(size_t)b * 1024 + r];
        }
        m += (int)__popcll(bal);
    }
    if (m > 256) m = 256;
    __syncthreads();

    float K = (float)ci * 2.0f;
    float ox1[4], oy1[4], ox2[4], oy2[4], sc[4];
    float nx1[4], ny1[4], nx2[4], ny2[4], ar[4];
    int flags = 0;
    #pragma unroll
    for (int t = 0; t < 4; ++t) {
        int j = t * 64 + lane;
        if (j < m) {
            ox1[t] = mem[wave][j][0]; oy1[t] = mem[wave][j][1];
            ox2[t] = mem[wave][j][2]; oy2[t] = mem[wave][j][3];
            sc[t]  = mem[wave][j][4];
            nx1[t] = ox1[t] + K; ny1[t] = oy1[t] + K;
            nx2[t] = ox2[t] + K; ny2[t] = oy2[t] + K;
            ar[t]  = (nx2[t] - nx1[t]) * (ny2[t] - ny1[t]);
            flags |= (1 << t);
        } else {
            ox1[t]=oy1[t]=ox2[t]=oy2[t]=sc[t]=0.0f;
            nx1[t]=ny1[t]=nx2[t]=ny2[t]=ar[t]=0.0f;
        }
    }

    // sequential greedy suppression (i ascending in sorted order)
    #pragma unroll
    for (int t = 0; t < 4; ++t) {
        for (int l = 0; l < 64; ++l) {
            int i = t * 64 + l;
            if (i >= m) break;                       // uniform
            int fi = __shfl(flags, l);               // keep[i], uniform
            if ((fi >> t) & 1) {
                float bx1 = __shfl(nx1[t], l), by1 = __shfl(ny1[t], l);
                float bx2 = __shfl(nx2[t], l), by2 = __shfl(ny2[t], l);
                float ba  = __shfl(ar[t], l);
                #pragma unroll
                for (int u = 0; u < 4; ++u) {
                    int j = u * 64 + lane;
                    if (j > i && j < m && ((flags >> u) & 1)) {
                        float ltx = fmaxf(bx1, nx1[u]), lty = fmaxf(by1, ny1[u]);
                        float rbx = fminf(bx2, nx2[u]), rby = fminf(by2, ny2[u]);
                        float wx = fmaxf(rbx - ltx, 0.0f), wy = fmaxf(rby - lty, 0.0f);
                        float inter = wx * wy;
                        float iou = inter / (ba + ar[u] - inter + 1e-8f);
                        if (iou > 0.5f) flags &= ~(1 << u);
                    }
                }
            }
        }
    }

    // emit: kept members in order -> rows [0, total), zeros -> rest of 200
    u64 bal0 = __ballot(flags & 1);
    u64 bal1 = __ballot((flags >> 1) & 1);
    u64 bal2 = __ballot((flags >> 2) & 1);
    u64 bal3 = __ballot((flags >> 3) & 1);
    int c0 = (int)__popcll(bal0), c1 = (int)__popcll(bal1);
    int c2 = (int)__popcll(bal2), c3 = (int)__popcll(bal3);
    int total = c0 + c1 + c2 + c3;
    size_t outBase = ((size_t)(b * NC + ci)) * TOPK * 5;
    u64 lmask = (((u64)1) << lane) - 1ull;
    int bases[4] = {0, c0, c0 + c1, c0 + c1 + c2};
    #pragma unroll
    for (int t = 0; t < 4; ++t) {
        if ((flags >> t) & 1) {
            u64 balT = (t == 0) ? bal0 : (t == 1) ? bal1 : (t == 2) ? bal2 : bal3;
            int rank = bases[t] + (int)__popcll(balT & lmask);
            if (rank < TOPK) {
                float* o = out + outBase + (size_t)rank * 5;
                o[0] = ox1[t]; o[1] = oy1[t]; o[2] = ox2[t]; o[3] = oy2[t]; o[4] = sc[t];
            }
        }
    }
    int start = total < TOPK ? total : TOPK;
    #pragma unroll
    for (int t = 0; t < 4; ++t) {
        int r = t * 64 + lane;
        if (r >= start && r < TOPK) {
            float* o = out + outBase + (size_t)r * 5;
            o[0] = 0.0f; o[1] = 0.0f; o[2] = 0.0f; o[3] = 0.0f; o[4] = 0.0f;
        }
    }
}

extern "C" void kernel_launch(void* const* d_in, const int* in_sizes, int n_in,
                              void* d_out, int out_size, void* d_ws, size_t ws_size,
                              hipStream_t stream) {
    (void)in_sizes; (void)n_in; (void)out_size; (void)ws_size;
    const float* conf    = (const float*)d_in[0];
    const float* regs    = (const float*)d_in[1];
    const float* anchors = (const float*)d_in[2];
    float* out = (float*)d_out;
    char* ws = (char*)d_ws;

    u32* hist1   = (u32*)(ws + OFF_HIST1);
    u32* hist2   = (u32*)(ws + OFF_HIST2);
    u32* hist3   = (u32*)(ws + OFF_HIST3);
    u32* candCnt = (u32*)(ws + OFF_CANDCNT);
    u32* state   = (u32*)(ws + OFF_STATE);
    u64* cand    = (u64*)(ws + OFF_CAND);
    float* boxes = (float*)(ws + OFF_BOXES);
    float* score = (float*)(ws + OFF_SCORE);
    int* clsSel  = (int*)(ws + OFF_CLSSEL);
    u32* vbits   = (u32*)(ws + OFF_VBITS);
    u8* cls      = (u8*)(ws + OFF_CLS);

    hipMemsetAsync(d_ws, 0, ZERO_BYTES, stream);

    const int BPI_R = (NA + 1023) / 1024;   // 108
    const int BPI_H = (NA + 2047) / 2048;   // 54

    k_reduce<<<NB * BPI_R, 256, 0, stream>>>(conf, vbits, cls, hist1);
    k_select<<<NB, 256, 0, stream>>>(state, hist1, 2048, 21);
    k_hist<<<NB * BPI_H, 256, 0, stream>>>(vbits, state, hist2, 2048, 21, 10);
    k_select<<<NB, 256, 0, stream>>>(state, hist2, 2048, 10);
    k_hist<<<NB * BPI_H, 256, 0, stream>>>(vbits, state, hist3, 1024, 10, 0);
    k_select<<<NB, 256, 0, stream>>>(state, hist3, 1024, 0);
    k_compact<<<NB * BPI_H, 256, 0, stream>>>(vbits, state, cand, candCnt);
    k_sort<<<NB, 256, 0, stream>>>(cand, candCnt);
    k_finalize<<<NB, 256, 0, stream>>>(cand, candCnt, cls, anchors, regs,
                                       boxes, score, clsSel);
    k_nms<<<NB * (NC / 4), 256, 0, stream>>>(boxes, score, clsSel, out);
}

// Round 2
// 220.781 us; speedup vs baseline: 1.3419x; 1.3419x over previous
//
#include <hip/hip_runtime.h>

typedef unsigned int u32;
typedef unsigned long long u64;
typedef unsigned char u8;

#define NB 8
#define NA 110000
#define NC 80
#define PRE 1000
#define TOPK 200
#define CAND_MAX 2048

// ---- workspace layout (bytes) ----
#define OFF_HF    0u          // fine hist  8*2048*4 = 65536
#define OFF_HC    65536u      // coarse hist 8*2048*4 = 65536
#define ZERO_BYTES 131072u
#define OFF_VBITS 131072u     // 8*110000*4 = 3520000
#define OFF_CLS   3651072u    // 8*110000*1 = 880000   -> total 4531072

// ============ K1: per-anchor max/argmax over 80 classes + fused histograms ============
// Fine hist: buckets of 1024 ulps over [0.875, 1)  (bucket 0 = highest scores).
// Coarse hist: vb>>21 for the (rare) values below 0.875.
__global__ __launch_bounds__(256) void k_reduce(const float* __restrict__ conf,
                                                u32* __restrict__ vbits,
                                                u8* __restrict__ cls,
                                                u32* __restrict__ gHF,
                                                u32* __restrict__ gHC) {
    const int BPI = (NA + 1023) / 1024;   // 108
    int b = blockIdx.x / BPI;
    int ch = blockIdx.x % BPI;
    __shared__ u32 hf[2048];
    __shared__ u32 hc[2048];
    for (int i = threadIdx.x; i < 2048; i += 256) { hf[i] = 0u; hc[i] = 0u; }
    __syncthreads();
    int base = ch * 1024;
    for (int k = 0; k < 4; ++k) {
        int a = base + k * 256 + threadIdx.x;
        if (a < NA) {
            const float4* p = reinterpret_cast<const float4*>(conf + ((size_t)b * NA + a) * NC);
            float m = -1.0f; int mi = 0;
            #pragma unroll
            for (int i = 0; i < 20; ++i) {
                float4 v = p[i];
                if (v.x > m) { m = v.x; mi = 4 * i + 0; }
                if (v.y > m) { m = v.y; mi = 4 * i + 1; }
                if (v.z > m) { m = v.z; mi = 4 * i + 2; }
                if (v.w > m) { m = v.w; mi = 4 * i + 3; }
            }
            cls[(size_t)b * NA + a] = (u8)mi;
            u32 vb = (m > 0.05f) ? __float_as_uint(m) : 0u;
            vbits[(size_t)b * NA + a] = vb;
            if (vb) {
                if (vb >= 0x3F600000u && vb <= 0x3F7FFFFFu) {
                    atomicAdd(&hf[(0x3F7FFFFFu - vb) >> 10], 1u);
                } else {
                    atomicAdd(&hc[vb >> 21], 1u);
                }
            }
        }
    }
    __syncthreads();
    for (int i = threadIdx.x; i < 2048; i += 256) {
        if (hf[i]) atomicAdd(&gHF[b * 2048 + i], hf[i]);
        if (hc[i]) atomicAdd(&gHC[b * 2048 + i], hc[i]);
    }
}

// ============ K2: select + compact + sort + decode + NMS, one block per image ============
#define K2T 512
__global__ __launch_bounds__(K2T) void k_main(const u32* __restrict__ vbits,
                                              const u8* __restrict__ cls,
                                              const float* __restrict__ anchors,
                                              const float* __restrict__ regs,
                                              const u32* __restrict__ gHF,
                                              const u32* __restrict__ gHC,
                                              float* __restrict__ out) {
    int b = blockIdx.x;
    int tid = threadIdx.x;
    int lane = tid & 63;
    int wave = tid >> 6;

    __shared__ u64 cand[CAND_MAX];          // 16 KB; reused as NMS member store
    __shared__ u32 histF[2048];             // 8 KB
    __shared__ float4 bxl[PRE];             // 16000 B
    __shared__ float scl[PRE];              // 4000 B
    __shared__ int   cll[PRE];              // 4000 B
    __shared__ u32 part[K2T];               // 2 KB
    __shared__ u32 ctrl[4];                 // [0]=threshold T, [1]=cand count

    // ---- Phase A: threshold select ----
    for (int i = tid; i < 2048; i += K2T) histF[i] = gHF[b * 2048 + i];
    __syncthreads();
    {
        u32 s = 0;
        #pragma unroll
        for (int j = 0; j < 4; ++j) s += histF[tid * 4 + j];
        part[tid] = s;
    }
    __syncthreads();
    if (tid == 0) {
        u32 T = 0; u32 cum = 0; int resolved = 0;
        for (int t = 0; t < K2T && !resolved; ++t) {
            if (cum + part[t] >= (u32)PRE) {
                for (int j = 0; j < 4; ++j) {
                    u32 c = histF[t * 4 + j];
                    if (cum + c >= (u32)PRE) {
                        u32 bk = (u32)(t * 4 + j);
                        T = 0x3F7FFFFFu - (bk << 10) - 1023u;   // min value in bucket bk
                        resolved = 1;
                        break;
                    }
                    cum += c;
                }
            } else {
                cum += part[t];
            }
        }
        if (!resolved) {
            // fallback: fewer than PRE values >= 0.875 (never for this input)
            u32 fineTot = 0;
            for (int t = 0; t < K2T; ++t) fineTot += part[t];
            if (fineTot >= (u32)PRE) {
                T = 0x3F600000u;
            } else {
                u32 need = (u32)PRE - fineTot; u32 cum2 = 0; T = 0;
                for (int cb = 506; cb >= 0; --cb) {
                    u32 c = gHC[b * 2048 + cb];
                    if (cum2 + c >= need) { T = ((u32)cb) << 21; break; }
                    cum2 += c;
                }
                if (T == 0) T = 1u;   // take all valid
            }
        }
        ctrl[0] = T;
        ctrl[1] = 0u;
    }
    __syncthreads();
    u32 T = ctrl[0];

    // ---- Phase B: compact candidates >= T into LDS (unordered; sort fixes order) ----
    {
        const uint4* vb4 = reinterpret_cast<const uint4*>(vbits + (size_t)b * NA);
        for (int i = tid; i < NA / 4; i += K2T) {
            uint4 v = vb4[i];
            u32 a0 = (u32)(4 * i);
            if (v.x >= T) { u32 s = atomicAdd(&ctrl[1], 1u); if (s < CAND_MAX) cand[s] = ((u64)v.x << 32) | (u64)(0xFFFFFFFFu - a0); }
            if (v.y >= T) { u32 s = atomicAdd(&ctrl[1], 1u); if (s < CAND_MAX) cand[s] = ((u64)v.y << 32) | (u64)(0xFFFFFFFFu - (a0 + 1u)); }
            if (v.z >= T) { u32 s = atomicAdd(&ctrl[1], 1u); if (s < CAND_MAX) cand[s] = ((u64)v.z << 32) | (u64)(0xFFFFFFFFu - (a0 + 2u)); }
            if (v.w >= T) { u32 s = atomicAdd(&ctrl[1], 1u); if (s < CAND_MAX) cand[s] = ((u64)v.w << 32) | (u64)(0xFFFFFFFFu - (a0 + 3u)); }
        }
    }
    __syncthreads();
    int n = (int)ctrl[1]; if (n > CAND_MAX) n = CAND_MAX;
    for (int i = tid; i < CAND_MAX; i += K2T) if (i >= n) cand[i] = 0ull;
    __syncthreads();

    // ---- Phase C: bitonic sort descending (key = score bits, then smaller anchor idx) ----
    for (int k = 2; k <= CAND_MAX; k <<= 1) {
        for (int j = k >> 1; j > 0; j >>= 1) {
            for (int i = tid; i < CAND_MAX; i += K2T) {
                int l = i ^ j;
                if (l > i) {
                    u64 A = cand[i], C = cand[l];
                    bool desc = ((i & k) == 0);
                    if (desc ? (A < C) : (A > C)) { cand[i] = C; cand[l] = A; }
                }
            }
            __syncthreads();
        }
    }

    // ---- Phase D: decode top-1000 boxes into LDS ----
    int nsel = n < PRE ? n : PRE;
    for (int r = tid; r < PRE; r += K2T) {
        if (r < nsel) {
            u64 key = cand[r];
            u32 vb = (u32)(key >> 32);
            u32 idx = 0xFFFFFFFFu - (u32)(key & 0xFFFFFFFFull);
            float4 an = reinterpret_cast<const float4*>(anchors)[idx];
            float4 rg = reinterpret_cast<const float4*>(regs)[(size_t)b * NA + idx];
            float ya = (an.x + an.z) * 0.5f;
            float xa = (an.y + an.w) * 0.5f;
            float ha = an.z - an.x;
            float wa = an.w - an.y;
            float w  = expf(rg.w) * wa;
            float h  = expf(rg.z) * ha;
            float yc = rg.x * ha + ya;
            float xc = rg.y * wa + xa;
            float x1 = xc - w * 0.5f, y1 = yc - h * 0.5f;
            float x2 = xc + w * 0.5f, y2 = yc + h * 0.5f;
            const float inv = 1.0f / 512.0f;
            float4 bx;
            bx.x = fminf(fmaxf(x1, 0.0f), 512.0f) * inv;
            bx.y = fminf(fmaxf(y1, 0.0f), 512.0f) * inv;
            bx.z = fminf(fmaxf(x2, 0.0f), 512.0f) * inv;
            bx.w = fminf(fmaxf(y2, 0.0f), 512.0f) * inv;
            bxl[r] = bx;
            scl[r] = __uint_as_float(vb);
            cll[r] = (int)cls[(size_t)b * NA + idx];
        } else {
            cll[r] = -1;
            scl[r] = 0.0f;
        }
    }
    __syncthreads();

    // ---- Phase E: per-class greedy NMS + emission (8 waves x 10 classes) ----
    float* M = reinterpret_cast<float*>(cand) + wave * 64 * 6;   // overlay on cand
    u64 lmask = (((u64)1) << lane) - 1ull;

    for (int kcl = 0; kcl < 10; ++kcl) {
        int ci = wave * 10 + kcl;

        // gather members of class ci in sorted order
        int m = 0;
        for (int chk = 0; chk < 16 && m < 64; ++chk) {
            int r = chk * 64 + lane;
            bool match = (r < PRE) && (cll[r] == ci);
            u64 bal = __ballot(match);
            int pos = m + (int)__popcll(bal & lmask);
            if (match && pos < 64) {
                float4 bx = bxl[r];
                M[pos * 6 + 0] = bx.x; M[pos * 6 + 1] = bx.y;
                M[pos * 6 + 2] = bx.z; M[pos * 6 + 3] = bx.w;
                M[pos * 6 + 4] = scl[r];
            }
            m += (int)__popcll(bal);
        }
        if (m > 64) m = 64;

        bool has = lane < m;
        float ox1 = 0, oy1 = 0, ox2 = 0, oy2 = 0, sc = 0;
        if (has) {
            ox1 = M[lane * 6 + 0]; oy1 = M[lane * 6 + 1];
            ox2 = M[lane * 6 + 2]; oy2 = M[lane * 6 + 3];
            sc  = M[lane * 6 + 4];
        }
        float K = (float)ci * 2.0f;
        float nx1 = ox1 + K, ny1 = oy1 + K, nx2 = ox2 + K, ny2 = oy2 + K;
        float ar = (nx2 - nx1) * (ny2 - ny1);
        bool alive = has;

        // sequential greedy suppression
        for (int l = 0; l < m; ++l) {
            int kl = __shfl((int)alive, l);
            float bx1 = __shfl(nx1, l), by1 = __shfl(ny1, l);
            float bx2 = __shfl(nx2, l), by2 = __shfl(ny2, l);
            float ba  = __shfl(ar, l);
            if (kl && lane > l && alive) {
                float ltx = fmaxf(bx1, nx1), lty = fmaxf(by1, ny1);
                float rbx = fminf(bx2, nx2), rby = fminf(by2, ny2);
                float wx = fmaxf(rbx - ltx, 0.0f), wy = fmaxf(rby - lty, 0.0f);
                float inter = wx * wy;
                float iou = inter / (ba + ar - inter + 1e-8f);
                if (iou > 0.5f) alive = false;
            }
        }

        // emit kept rows in order, then zero-fill to 200 rows
        u64 bal = __ballot(alive);
        int total = (int)__popcll(bal);
        size_t outBase = ((size_t)(b * NC + ci)) * TOPK * 5;
        if (alive) {
            int rank = (int)__popcll(bal & lmask);
            if (rank < TOPK) {
                float* o = out + outBase + (size_t)rank * 5;
                o[0] = ox1; o[1] = oy1; o[2] = ox2; o[3] = oy2; o[4] = sc;
            }
        }
        int start = total < TOPK ? total : TOPK;
        for (int idx2 = start * 5 + lane; idx2 < TOPK * 5; idx2 += 64)
            out[outBase + idx2] = 0.0f;
    }
}

extern "C" void kernel_launch(void* const* d_in, const int* in_sizes, int n_in,
                              void* d_out, int out_size, void* d_ws, size_t ws_size,
                              hipStream_t stream) {
    (void)in_sizes; (void)n_in; (void)out_size; (void)ws_size;
    const float* conf    = (const float*)d_in[0];
    const float* regs    = (const float*)d_in[1];
    const float* anchors = (const float*)d_in[2];
    float* out = (float*)d_out;
    char* ws = (char*)d_ws;

    u32* gHF   = (u32*)(ws + OFF_HF);
    u32* gHC   = (u32*)(ws + OFF_HC);
    u32* vbits = (u32*)(ws + OFF_VBITS);
    u8*  cls   = (u8*)(ws + OFF_CLS);

    hipMemsetAsync(d_ws, 0, ZERO_BYTES, stream);

    const int BPI_R = (NA + 1023) / 1024;   // 108
    k_reduce<<<NB * BPI_R, 256, 0, stream>>>(conf, vbits, cls, gHF, gHC);
    k_main<<<NB, K2T, 0, stream>>>(vbits, cls, anchors, regs, gHF, gHC, out);
}